// Round 11
// baseline (178.684 us; speedup 1.0000x reference)
//
#include <hip/hip_runtime.h>
#include <hip/hip_bf16.h>

// RecursiveNN, perfect binary tree. N=262144 leaves, IN=64, HID=128.
// SETTLED: inputs fp32 jax-layout ([K,N] weights), output fp32[128].
// R10: 168.5us (kfront 64: VALUBusy 41%, MfmaUtil 14%, occ 19%; tail ~15;
// unexplained ~90us suspected harness restore/poison floor).
// R11: (1) 512 blocks x 512 thr, 4 subtrees (512 leaves)/block -> W-frag
// gather amortized 4x, 16 waves/CU, single dispatch round; (2) bias folded
// into MFMA acc-init + weights/biases pre-scaled by 2*log2(e) -> tanh =
// exp2,add,rcp,fma (no mul); (3) inter-kernel rows packed bf16 -> kmid/ktail
// staging is pure uint4 copy (no cvt).
//
// In-place in leaf_x buffer XB (no d_ws):
//  kfront b: 4x(leaf GEMM + levels 1..5 on 128 leaves) -> 16 bf16 rows
//            (64 u32 each) at words XB[32768b + j*64], j=0..15.
//  kmid t (64 blocks): stage 128 rows (kfront blocks 8t..8t+7), levels 6..12
//            -> 1 bf16 row at words XB[262144t + 2048].
//  ktail: 64 rows -> levels 13..18 -> root fp32[128] -> d_out.
// H LDS: row stride 136 bf16, col swizzle c ^ (((row>>3)&3)<<3).

typedef unsigned short u16;
typedef unsigned int u32;
typedef __attribute__((ext_vector_type(8))) short bf16x8;   // 8 bf16, 4 VGPR
typedef __attribute__((ext_vector_type(4))) float f32x4;

#define SC 2.8853900817779268f   // 2*log2(e), folded into weights/biases

__device__ __forceinline__ u16 f2bf(float f) {
    __hip_bfloat16 h = __float2bfloat16(f);   // RNE
    return *(u16*)&h;
}
__device__ __forceinline__ u32 f2bf_pk(float a, float b) {
    __hip_bfloat162 h = __float22bfloat162_rn(make_float2(a, b));
    return *(u32*)&h;
}
// tanh with pre-scaled arg y = 2*log2(e)*x: 1 - 2/(2^y + 1). NaN-free.
__device__ __forceinline__ float tanh_pre(float y) {
#if __has_builtin(__builtin_amdgcn_exp2f) && __has_builtin(__builtin_amdgcn_rcpf)
    float t = __builtin_amdgcn_exp2f(y);
    float r = __builtin_amdgcn_rcpf(t + 1.0f);
    return __builtin_fmaf(-2.0f, r, 1.0f);
#else
    float e = __expf(y * 0.6931471805599453f);
    return 1.0f - 2.0f / (e + 1.0f);
#endif
}
__device__ __forceinline__ int swz(int row, int c) {
    return c ^ (((row >> 3) & 3) << 3);
}

#define MFMA16(a, b, c) __builtin_amdgcn_mfma_f32_16x16x32_bf16((a), (b), (c), 0, 0, 0)

// ---- B-frag pair from global W (scaled): lane owns cols (c0, c0+1) ---------
__device__ __forceinline__ void pair_frags_g(const float* __restrict__ W,
                                             int kbase, int c0,
                                             bf16x8& f0, bf16x8& f1) {
#pragma unroll
    for (int j = 0; j < 8; ++j) {
        float2 v = *(const float2*)(W + (size_t)(kbase + j) * 128 + c0);
        f0[j] = (short)f2bf(v.x * SC);
        f1[j] = (short)f2bf(v.y * SC);
    }
}
__device__ __forceinline__ void load_level_frags_g(
    const float* __restrict__ Wl, const float* __restrict__ Wr,
    int quad, int c0, bf16x8 (&bw)[8][2]) {
#pragma unroll
    for (int kc = 0; kc < 8; ++kc) {
        const float* W = (kc < 4) ? Wl : Wr;
        pair_frags_g(W, (kc & 3) * 32 + quad * 8, c0, bw[kc][0], bw[kc][1]);
    }
}

// ---- W -> transposed LDS (kmid/ktail), scaled: Wt[mat][n][k] stride 136 ----
__device__ __forceinline__ void stage_w_t(u16* Wt, const float* __restrict__ Wl,
                                          const float* __restrict__ Wr, int tid) {
#pragma unroll
    for (int t = 0; t < 32; ++t) {
        int i4 = tid + 256 * t;                    // 0..8191
        const float* W = (i4 < 4096) ? Wl : Wr;
        u16* dst = Wt + ((i4 < 4096) ? 0 : 128 * 136);
        int rem = i4 & 4095;
        int k = rem >> 5;                          // 0..127
        int n4 = (rem & 31) << 2;                  // 0..124
        float4 v = *(const float4*)(W + (size_t)k * 128 + n4);
        dst[(n4 + 0) * 136 + k] = f2bf(v.x * SC);
        dst[(n4 + 1) * 136 + k] = f2bf(v.y * SC);
        dst[(n4 + 2) * 136 + k] = f2bf(v.z * SC);
        dst[(n4 + 3) * 136 + k] = f2bf(v.w * SC);
    }
}
__device__ __forceinline__ void load_level_frags_lds(
    const u16* Wt, int quad, int c0, bf16x8 (&bw)[8][2]) {
#pragma unroll
    for (int kc = 0; kc < 8; ++kc) {
        const int base = (kc < 4) ? 0 : 128 * 136;
        const int kb = (kc & 3) * 32 + quad * 8;
        bw[kc][0] = *(const bf16x8*)(Wt + base + c0 * 136 + kb);
        bw[kc][1] = *(const bf16x8*)(Wt + base + (c0 + 1) * 136 + kb);
    }
}

// ---- pairwise levels: 2*Mfirst rows -> Mlast rows; final level writes ------
// FB=true: packed-bf16 u32 rows (64 u32/row); FB=false: fp32 float2 rows.
template <bool FB>
__device__ __forceinline__ void run_levels_mfma(
    u16* b0, u16* b1, int Mfirst, int Mlast, const bf16x8 (&bw)[8][2],
    float sb0, float sb1, void* finalOut,
    int rstart, int rstep, int cg, int quad, int lq, int c0) {
    u16* in = b0;
    u16* out = b1;
    for (int M = Mfirst; M >= Mlast; M >>= 1) {
        const int ntiles = (M + 15) >> 4;
        for (int rt = rstart; rt < ntiles; rt += rstep) {
            const int r0e = rt * 16;
            bf16x8 a[8];
#pragma unroll
            for (int kc = 0; kc < 8; ++kc) {
                const int row = 2 * (r0e + lq) + (kc >> 2);
                const int kb = (kc & 3) * 32 + quad * 8;
                a[kc] = *(const bf16x8*)(in + row * 136 + swz(row, kb));
            }
            f32x4 ac0 = {sb0, sb0, sb0, sb0};   // bias pre-loaded in acc
            f32x4 ac1 = {sb1, sb1, sb1, sb1};
#pragma unroll
            for (int kc = 0; kc < 8; ++kc) {
                ac0 = MFMA16(a[kc], bw[kc][0], ac0);
                ac1 = MFMA16(a[kc], bw[kc][1], ac1);
            }
#pragma unroll
            for (int r = 0; r < 4; ++r) {
                const int ro = r0e + quad * 4 + r;
                if (ro < M) {
                    float v0 = tanh_pre(ac0[r]);
                    float v1 = tanh_pre(ac1[r]);
                    if (M == Mlast) {
                        if (FB)
                            ((u32*)finalOut)[ro * 64 + 16 * cg + lq] = f2bf_pk(v0, v1);
                        else
                            *(float2*)((float*)finalOut + ro * 128 + c0) =
                                make_float2(v0, v1);
                    } else {
                        *(u32*)(out + ro * 136 + swz(ro, c0)) = f2bf_pk(v0, v1);
                    }
                }
            }
        }
        __syncthreads();
        u16* tmp = in; in = out; out = tmp;
    }
}

// ---- kfront: 4 subtrees x (leaf GEMM + levels 1..5) ------------------------
__global__ __launch_bounds__(512, 2) void kfront(
    float* XB, const float* __restrict__ Win, const float* __restrict__ bin,
    const float* __restrict__ Wl, const float* __restrict__ Wr,
    const float* __restrict__ bl, const float* __restrict__ br) {
    __shared__ __align__(16) u16 H0[128 * 136];   // 34816 B
    __shared__ __align__(16) u16 POOL[128 * 72];  // 18432 B: Xa, then H1

    const int tid = threadIdx.x;
    const int w = tid >> 6, lane = tid & 63, quad = lane >> 4, lq = lane & 15;
    const int cg = w & 3, rh = w >> 2;            // col-group, row-half
    const int c0 = 32 * cg + 2 * lq;              // pair (c0, c0+1)
    const int b = blockIdx.x;
    u16* Xa = POOL;   // [128][72] bf16 leaf inputs
    u16* H1 = POOL;   // [64][136] during levels (Xa dead)

    bf16x8 bwin[2][2];
#pragma unroll
    for (int kc = 0; kc < 2; ++kc)
        pair_frags_g(Win, kc * 32 + quad * 8, c0, bwin[kc][0], bwin[kc][1]);
    bf16x8 bw[8][2];
    load_level_frags_g(Wl, Wr, quad, c0, bw);

    const float2 binp = *(const float2*)(bin + c0);
    const float2 blp = *(const float2*)(bl + c0);
    const float2 brp = *(const float2*)(br + c0);
    const float sbin0 = binp.x * SC, sbin1 = binp.y * SC;
    const float sbs0 = (blp.x + brp.x) * SC, sbs1 = (blp.y + brp.y) * SC;

    for (int s = 0; s < 4; ++s) {
        const float* Xg = XB + (size_t)b * 32768 + s * 8192;
#pragma unroll
        for (int t = 0; t < 4; ++t) {             // 2048 float4 / 512 thr
            int i4 = tid + 512 * t;
            int r = i4 >> 4, k4 = (i4 & 15) << 2;
            float4 v = *(const float4*)(Xg + r * 64 + k4);
            *(uint2*)(Xa + r * 72 + k4) =
                make_uint2(f2bf_pk(v.x, v.y), f2bf_pk(v.z, v.w));
        }
        __syncthreads();
        // leaf GEMM: 8 row-tiles split by row-half
        for (int rt = rh; rt < 8; rt += 2) {
            const int rowa = rt * 16 + lq;
            bf16x8 a0 = *(const bf16x8*)(Xa + rowa * 72 + quad * 8);
            bf16x8 a1 = *(const bf16x8*)(Xa + rowa * 72 + 32 + quad * 8);
            f32x4 ac0 = {sbin0, sbin0, sbin0, sbin0};
            f32x4 ac1 = {sbin1, sbin1, sbin1, sbin1};
            ac0 = MFMA16(a0, bwin[0][0], ac0);
            ac0 = MFMA16(a1, bwin[1][0], ac0);
            ac1 = MFMA16(a0, bwin[0][1], ac1);
            ac1 = MFMA16(a1, bwin[1][1], ac1);
#pragma unroll
            for (int r = 0; r < 4; ++r) {
                const int ro = rt * 16 + quad * 4 + r;
                *(u32*)(H0 + ro * 136 + swz(ro, c0)) =
                    f2bf_pk(tanh_pre(ac0[r]), tanh_pre(ac1[r]));
            }
        }
        __syncthreads();   // H0 complete; Xa reads done (H1 aliases Xa)
        // levels 1..5 -> 4 bf16 rows at words XB[32768b + (4s+i)*64]
        run_levels_mfma<true>(H0, H1, 64, 4, bw, sbs0, sbs1,
                              (u32*)XB + (size_t)b * 32768 + s * 256,
                              rh, 2, cg, quad, lq, c0);
    }
}

// ---- kmid: 64 blocks, 128 bf16 rows, levels 6..12 -> 1 bf16 row ------------
__global__ __launch_bounds__(256) void kmid(
    float* XB, const float* __restrict__ Wl, const float* __restrict__ Wr,
    const float* __restrict__ bl, const float* __restrict__ br) {
    __shared__ __align__(16) u16 H0[128 * 136];
    __shared__ __align__(16) u16 H1[64 * 136];
    __shared__ __align__(16) u16 Wt[2 * 128 * 136];   // 69632 B

    const int tid = threadIdx.x;
    const int w = tid >> 6, lane = tid & 63, quad = lane >> 4, lq = lane & 15;
    const int t = blockIdx.x;
    const int c0 = 32 * w + 2 * lq;

    stage_w_t(Wt, Wl, Wr, tid);
    const u32* XW = (const u32*)XB;
#pragma unroll
    for (int it = 0; it < 8; ++it) {              // 128 rows x 64 u32
        int L = (tid + 256 * it) * 4;             // u32 index
        int r = L >> 6;                           // 0..127
        int c = L & 63;                           // 0,4,...,60
        uint4 v = *(const uint4*)(XW + (size_t)32768 * (8 * t + (r >> 4)) +
                                  64 * (r & 15) + c);
        *(uint4*)(H0 + r * 136 + swz(r, 2 * c)) = v;
    }
    const float2 blp = *(const float2*)(bl + c0);
    const float2 brp = *(const float2*)(br + c0);
    const float sbs0 = (blp.x + brp.x) * SC, sbs1 = (blp.y + brp.y) * SC;
    __syncthreads();

    bf16x8 bw[8][2];
    load_level_frags_lds(Wt, quad, c0, bw);
    run_levels_mfma<true>(H0, H1, 64, 1, bw, sbs0, sbs1,
                          (u32*)XB + (size_t)262144 * t + 2048,
                          0, 1, w, quad, lq, c0);
}

// ---- ktail: 64 bf16 rows, levels 13..18 -> root fp32 -----------------------
__global__ __launch_bounds__(256) void ktail(
    const float* XB, const float* __restrict__ Wl, const float* __restrict__ Wr,
    const float* __restrict__ bl, const float* __restrict__ br,
    float* __restrict__ out) {
    __shared__ __align__(16) u16 H0[64 * 136];
    __shared__ __align__(16) u16 H1[64 * 136];
    __shared__ __align__(16) u16 Wt[2 * 128 * 136];

    const int tid = threadIdx.x;
    const int w = tid >> 6, lane = tid & 63, quad = lane >> 4, lq = lane & 15;
    const int c0 = 32 * w + 2 * lq;

    stage_w_t(Wt, Wl, Wr, tid);
    const u32* XW = (const u32*)XB;
#pragma unroll
    for (int it = 0; it < 4; ++it) {              // 64 rows x 64 u32
        int L = (tid + 256 * it) * 4;
        int r = L >> 6;                           // 0..63
        int c = L & 63;
        uint4 v = *(const uint4*)(XW + (size_t)262144 * r + 2048 + c);
        *(uint4*)(H0 + r * 136 + swz(r, 2 * c)) = v;
    }
    const float2 blp = *(const float2*)(bl + c0);
    const float2 brp = *(const float2*)(br + c0);
    const float sbs0 = (blp.x + brp.x) * SC, sbs1 = (blp.y + brp.y) * SC;
    __syncthreads();

    bf16x8 bw[8][2];
    load_level_frags_lds(Wt, quad, c0, bw);
    run_levels_mfma<false>(H0, H1, 32, 1, bw, sbs0, sbs1, out,
                           0, 1, w, quad, lq, c0);
}

// ---- host ------------------------------------------------------------------
extern "C" void kernel_launch(void* const* d_in, const int* in_sizes, int n_in,
                              void* d_out, int out_size, void* d_ws, size_t ws_size,
                              hipStream_t stream) {
    float* XB = (float*)d_in[0];              // consumed then reused in-place
    const float* Win = (const float*)d_in[1];
    const float* bin = (const float*)d_in[2];
    const float* Wl  = (const float*)d_in[3];
    const float* bl  = (const float*)d_in[4];
    const float* Wr  = (const float*)d_in[5];
    const float* br  = (const float*)d_in[6];
    float* out = (float*)d_out;

    kfront<<<512, 512, 0, stream>>>(XB, Win, bin, Wl, Wr, bl, br);
    kmid<<<64, 256, 0, stream>>>(XB, Wl, Wr, bl, br);
    ktail<<<1, 256, 0, stream>>>(XB, Wl, Wr, bl, br, out);
}